// Round 4
// baseline (361.280 us; speedup 1.0000x reference)
//
#include <hip/hip_runtime.h>
#include <hip/hip_bf16.h>

typedef __bf16 bf16x8 __attribute__((ext_vector_type(8)));
typedef float f32x4 __attribute__((ext_vector_type(4)));
typedef unsigned int u32;
typedef u32 u32x4 __attribute__((ext_vector_type(4)));

#define MFMA16(a, b, c) __builtin_amdgcn_mfma_f32_16x16x32_bf16(a, b, c, 0, 0, 0)

static __device__ __forceinline__ unsigned short f2b(float f) {
    __hip_bfloat16 b = __float2bfloat16(f);
    return __builtin_bit_cast(unsigned short, b);
}
static __device__ __forceinline__ float b2f(unsigned short u) {
    u32 v = ((u32)u) << 16;
    return __builtin_bit_cast(float, v);
}
static __device__ __forceinline__ u32 pk2(float lo, float hi) {  // 2x trunc-bf16 pack
    return (__builtin_bit_cast(u32, lo) >> 16) | (__builtin_bit_cast(u32, hi) & 0xFFFF0000u);
}
static __device__ __forceinline__ void glds16(const void* g, void* l) {
    __builtin_amdgcn_global_load_lds((const __attribute__((address_space(1))) u32*)g,
                                     (__attribute__((address_space(3))) u32*)l, 16, 0, 0);
}

// ---------------- fp32 -> bf16 convert (activations), 8 elems/thread, z picks src ------
__global__ __launch_bounds__(256) void cvt2_kernel(const float* __restrict__ s0,
        const float* __restrict__ s1, unsigned short* __restrict__ d0,
        unsigned short* __restrict__ d1) {
    const float* src = blockIdx.y ? s1 : s0;
    unsigned short* dst = blockIdx.y ? d1 : d0;
    const size_t i = ((size_t)blockIdx.x * 256 + threadIdx.x) * 8;
    float4 a = *(const float4*)(src + i);
    float4 b = *(const float4*)(src + i + 4);
    ushort4 u0 = { f2b(a.x), f2b(a.y), f2b(a.z), f2b(a.w) };
    ushort4 u1 = { f2b(b.x), f2b(b.y), f2b(b.z), f2b(b.w) };
    *(ushort4*)(dst + i) = u0;
    *(ushort4*)(dst + i + 4) = u1;
}

// ---------------- weight transpose + bf16 cast: Wt[n][k] = bf16(W[k][n]) ----------------
__global__ void wt_kernel(const float* __restrict__ W0, const float* __restrict__ W1,
                          const float* __restrict__ W2, unsigned short* __restrict__ T0,
                          unsigned short* __restrict__ T1, unsigned short* __restrict__ T2) {
    const float* W = blockIdx.z == 0 ? W0 : (blockIdx.z == 1 ? W1 : W2);
    unsigned short* T = blockIdx.z == 0 ? T0 : (blockIdx.z == 1 ? T1 : T2);
    __shared__ float tile[32][33];
    const int n0 = blockIdx.x * 32, k0 = blockIdx.y * 32;
    const int tx = threadIdx.x, ty = threadIdx.y;  // block (32, 8)
#pragma unroll
    for (int i = 0; i < 4; i++)
        tile[ty + 8 * i][tx] = W[(size_t)(k0 + ty + 8 * i) * 1024 + n0 + tx];
    __syncthreads();
#pragma unroll
    for (int i = 0; i < 4; i++)
        T[(size_t)(n0 + ty + 8 * i) * 1024 + k0 + tx] = f2b(tile[tx][ty + 8 * i]);
}

// ---------------- projection GEMM, BK=64 (m97-style): dst = bf16(A @ Wt^T) -------------
// A: [8192][1024] bf16.  Wt: [1024 n][1024 k] bf16.  blockIdx.z picks A/Wt/dst pair.
// vmode 0: dst[(b*16+h)*2048 + s][64] (Q,K)   vmode 1: dst[(b*16+h)*64 + d][2048] (V^T)
__global__ __launch_bounds__(256) void proj_kernel(
        const unsigned short* __restrict__ A0, const unsigned short* __restrict__ A1,
        const unsigned short* __restrict__ W0, const unsigned short* __restrict__ W1,
        unsigned short* __restrict__ D0, unsigned short* __restrict__ D1, const int vmode) {
    __shared__ unsigned short smem[17408];   // staging 32 KB (2x [2][128][32]) | Tw 34 KB
    unsigned short* As = smem;
    unsigned short* Bs = smem + 8192;
    const unsigned short* A  = blockIdx.z ? A1 : A0;
    const unsigned short* Wt = blockIdx.z ? W1 : W0;
    unsigned short* dst      = blockIdx.z ? D1 : D0;
    const int m0 = blockIdx.x * 128, n0 = blockIdx.y * 128;  // x=m (64): same-A -> same XCD
    const int tid = threadIdx.x;
    const int w = tid >> 6, lane = tid & 63, quad = lane >> 4, l16 = lane & 15;
    const int wr = (w >> 1) * 64, wc = (w & 1) * 64;
    // staging map: idx in [0,1024): panel=idx>>9 (k-half), row=(idx>>2)&127, c=idx&3
    const unsigned short* ap[4];
    const unsigned short* bp[4];
#pragma unroll
    for (int i = 0; i < 4; i++) {
        int idx = tid + i * 256;
        int row = (idx >> 2) & 127, ch = (idx >> 9) * 4 + (idx & 3);
        ap[i] = A + (size_t)(m0 + row) * 1024 + ch * 8;
        bp[i] = Wt + (size_t)(n0 + row) * 1024 + ch * 8;
    }
    f32x4 acc[4][4] = {};
    for (int kb = 0; kb < 16; kb++) {
        __syncthreads();
#pragma unroll
        for (int i = 0; i < 4; i++) {
            glds16(ap[i], &As[(tid + i * 256) * 8]);
            glds16(bp[i], &Bs[(tid + i * 256) * 8]);
            ap[i] += 64; bp[i] += 64;
        }
        __syncthreads();
#pragma unroll
        for (int kp = 0; kp < 2; kp++) {
            bf16x8 af[4], bf[4];
#pragma unroll
            for (int mt = 0; mt < 4; mt++)
                af[mt] = *(const bf16x8*)&As[kp * 4096 + (wr + mt * 16 + l16) * 32 + quad * 8];
#pragma unroll
            for (int nt = 0; nt < 4; nt++)
                bf[nt] = *(const bf16x8*)&Bs[kp * 4096 + (wc + nt * 16 + l16) * 32 + quad * 8];
#pragma unroll
            for (int mt = 0; mt < 4; mt++)
#pragma unroll
                for (int nt = 0; nt < 4; nt++)
                    acc[mt][nt] = MFMA16(af[mt], bf[nt], acc[mt][nt]);
        }
    }
    __syncthreads();                         // staging dead; reuse as transpose buffer
    unsigned short* Tw = smem + w * 4352;    // per-wave 64 x 68
    if (vmode == 0) {                        // rows = tokens, cols = channels
#pragma unroll
        for (int mt = 0; mt < 4; mt++)
#pragma unroll
            for (int nt = 0; nt < 4; nt++)
#pragma unroll
                for (int r = 0; r < 4; r++)
                    Tw[(mt * 16 + quad * 4 + r) * 68 + nt * 16 + l16] = f2b(acc[mt][nt][r]);
    } else {                                 // rows = d, cols = tokens
#pragma unroll
        for (int mt = 0; mt < 4; mt++)
#pragma unroll
            for (int nt = 0; nt < 4; nt++)
#pragma unroll
                for (int r = 0; r < 4; r++)
                    Tw[(nt * 16 + l16) * 68 + mt * 16 + quad * 4 + r] = f2b(acc[mt][nt][r]);
    }
    const int gr0 = m0 + wr, gc0 = n0 + wc;  // wave-private buffer: in-wave order, no barrier
    const int b = gr0 >> 11, s0 = gr0 & 2047, h = gc0 >> 6;
    if (vmode == 0) {
        const size_t obase = (size_t)(b * 16 + h) * 2048;
#pragma unroll
        for (int j = 0; j < 16; j++) {
            int row = j * 4 + quad;          // token offset
            uint2 val = *(const uint2*)&Tw[row * 68 + l16 * 4];
            *(uint2*)(dst + (obase + s0 + row) * 64 + l16 * 4) = val;
        }
    } else {
        const size_t vbase = (size_t)(b * 16 + h) * 64 * 2048;
#pragma unroll
        for (int j = 0; j < 16; j++) {
            int row = j * 4 + quad;          // d
            uint2 val = *(const uint2*)&Tw[row * 68 + l16 * 4];
            *(uint2*)(dst + vbase + (size_t)row * 2048 + s0 + l16 * 4) = val;
        }
    }
}

// ---------------- fused masked-causal flash attention (BQ=64, S^T form) ----------------
// Qp,Kp: [bh][2048][64] bf16.  Vt: [bh][64][2048] bf16.  out: [b][s][1024] fp32.
// S^T = K Q^T so P exits QK^T already in A-operand lane distribution (lane = q);
// PV uses a k-permuted MFMA (valid since V fragments use the same permutation).
// Fixed-max softmax e^(s-8): masked entries underflow to exact 0. Degenerate rows
// (all-prefix-masked, l==0) get the reference's uniform average via rare fix-up.
// grid (bh=64, pair=16): q-tiles {y, 31-y} -> uniform 33 kv-iters; same-bh same-XCD.
__global__ __launch_bounds__(256) void attn_kernel(
        const unsigned short* __restrict__ Qp, const unsigned short* __restrict__ Kp,
        const unsigned short* __restrict__ Vt, const float* __restrict__ vmask,
        const float* __restrict__ qmask, float* __restrict__ out) {
    __shared__ unsigned short Ks[4096];      // [d-half][kv 64][32]
    __shared__ unsigned short Vts[4096];     // [kv-half][d 64][32]
    __shared__ float Vmb[2048];              // key-mask bias (log2 domain), incl. -8
    const int bh = blockIdx.x, b = bh >> 4, h = bh & 15;
    const int tid = threadIdx.x;
    const int w = tid >> 6, lane = tid & 63, quad = lane >> 4, l16 = lane & 15;
    const size_t base = (size_t)bh * 2048 * 64;
    const float C1 = 0.18033688f;            // 0.125 * log2(e)
    const float C0 = -11.54156036f;          // -8 * log2(e)
    const float CM = -1.44269504e10f;        // -1e10 * log2(e)
    for (int i = tid; i < 2048; i += 256)
        Vmb[i] = (vmask[b * 2048 + i] != 0.f) ? C0 : (C0 + CM);

    // per-thread staging pointers (fixed row/chunk; tile offset added per kt)
    const int i0 = tid, i1 = tid + 256;      // panel=idx>>8, row=(idx>>2)&63, c=idx&3
    const unsigned short* kp0 = Kp + base + (size_t)((i0 >> 2) & 63) * 64 + (i0 >> 8) * 32 + (i0 & 3) * 8;
    const unsigned short* kp1 = Kp + base + (size_t)((i1 >> 2) & 63) * 64 + (i1 >> 8) * 32 + (i1 & 3) * 8;
    const unsigned short* vp0 = Vt + base + (size_t)((i0 >> 2) & 63) * 2048 + (i0 >> 8) * 32 + (i0 & 3) * 8;
    const unsigned short* vp1 = Vt + base + (size_t)((i1 >> 2) & 63) * 2048 + (i1 >> 8) * 32 + (i1 & 3) * 8;

    for (int pass = 0; pass < 2; pass++) {
        const int qt = pass ? 31 - blockIdx.y : blockIdx.y;
        const int q0 = qt * 64;
        bf16x8 qa[2];
#pragma unroll
        for (int ks = 0; ks < 2; ks++)
            qa[ks] = *(const bf16x8*)(Qp + base +
                (size_t)(q0 + w * 16 + l16) * 64 + ks * 32 + quad * 8);
        f32x4 o[4] = {};
        float lsum = 0.f;

        auto do_tile = [&](int kt, bool diag) __attribute__((always_inline)) {
            __syncthreads();                 // prev-iter/prev-pass LDS reads done
            glds16(kp0 + (size_t)kt * 4096, &Ks[i0 * 8]);
            glds16(kp1 + (size_t)kt * 4096, &Ks[i1 * 8]);
            glds16(vp0 + kt * 64, &Vts[i0 * 8]);
            glds16(vp1 + kt * 64, &Vts[i1 * 8]);
            __syncthreads();

            f32x4 st[4];                     // S^T = K Q^T: col=l16=q, row=quad*4+r=kv
#pragma unroll
            for (int nt = 0; nt < 4; nt++) {
                bf16x8 kf0 = *(const bf16x8*)&Ks[(nt * 16 + l16) * 32 + quad * 8];
                bf16x8 kf1 = *(const bf16x8*)&Ks[2048 + (nt * 16 + l16) * 32 + quad * 8];
                f32x4 z = {};
                z = MFMA16(kf0, qa[0], z);
                z = MFMA16(kf1, qa[1], z);
                st[nt] = z;
            }
            float p[4][4];
#pragma unroll
            for (int nt = 0; nt < 4; nt++) {
                f32x4 vb4 = *(const f32x4*)&Vmb[kt * 64 + nt * 16 + quad * 4];
#pragma unroll
                for (int r = 0; r < 4; r++) {
                    float pv = __builtin_amdgcn_exp2f(st[nt][r] * C1 + vb4[r]);
                    if (diag)                // causal mask only on the diagonal tile
                        pv = (nt * 16 + quad * 4 + r > w * 16 + l16) ? 0.f : pv;
                    p[nt][r] = pv;
                    lsum += pv;
                }
            }
            // O += P V with k-permutation k̂(quad,j) = h2*32 + (j<4 ? quad*4+j : 16+quad*4+j-4)
#pragma unroll
            for (int h2 = 0; h2 < 2; h2++) {
                u32x4 pw = { pk2(p[2 * h2][0], p[2 * h2][1]), pk2(p[2 * h2][2], p[2 * h2][3]),
                             pk2(p[2 * h2 + 1][0], p[2 * h2 + 1][1]), pk2(p[2 * h2 + 1][2], p[2 * h2 + 1][3]) };
                bf16x8 pa = __builtin_bit_cast(bf16x8, pw);
#pragma unroll
                for (int dt = 0; dt < 4; dt++) {
                    const unsigned short* vp = &Vts[h2 * 2048 + (dt * 16 + l16) * 32 + quad * 4];
                    uint2 v0 = *(const uint2*)vp;
                    uint2 v1 = *(const uint2*)(vp + 16);
                    u32x4 vw = { v0.x, v0.y, v1.x, v1.y };
                    o[dt] = MFMA16(pa, __builtin_bit_cast(bf16x8, vw), o[dt]);
                }
            }
        };
        for (int kt = 0; kt < qt; kt++) do_tile(kt, false);
        do_tile(qt, true);

        float lf = lsum;                     // reduce across quads: l[q = w*16 + l16]
        lf += __shfl_xor(lf, 16);
        lf += __shfl_xor(lf, 32);
        float lr[4];
#pragma unroll
        for (int r = 0; r < 4; r++) lr[r] = __shfl(lf, quad * 4 + r);
        // degenerate rows (entire causal prefix v-masked): uniform average over
        // {kv <= q} u {kv > q : vmask==1}
        bool deg = (lr[0] == 0.f) | (lr[1] == 0.f) | (lr[2] == 0.f) | (lr[3] == 0.f);
        if (__any((int)deg)) {
#pragma unroll
            for (int r = 0; r < 4; r++)
                if (lr[r] == 0.f) {
                    const int qr = q0 + w * 16 + quad * 4 + r;
                    float cnt = 0.f;
                    float oacc[4] = {0.f, 0.f, 0.f, 0.f};
                    for (int kv = 0; kv < 2048; kv++) {
                        bool keep = (kv <= qr) || (vmask[b * 2048 + kv] != 0.f);
                        if (keep) {
                            cnt += 1.f;
#pragma unroll
                            for (int dt = 0; dt < 4; dt++)
                                oacc[dt] += b2f(Vt[base + (size_t)(dt * 16 + l16) * 2048 + kv]);
                        }
                    }
                    lr[r] = cnt;
#pragma unroll
                    for (int dt = 0; dt < 4; dt++) o[dt][r] = oacc[dt];
                }
        }
#pragma unroll
        for (int r = 0; r < 4; r++) {
            int q = q0 + w * 16 + quad * 4 + r;
            float sc = qmask[b * 2048 + q] / lr[r];
#pragma unroll
            for (int dt = 0; dt < 4; dt++)
                out[(size_t)(b * 2048 + q) * 1024 + h * 64 + dt * 16 + l16] = o[dt][r] * sc;
        }
    }
}

extern "C" void kernel_launch(void* const* d_in, const int* in_sizes, int n_in,
                              void* d_out, int out_size, void* d_ws, size_t ws_size,
                              hipStream_t stream) {
    const float* q  = (const float*)d_in[0];
    const float* k  = (const float*)d_in[1];
    const float* v  = (const float*)d_in[2];
    const float* vm = (const float*)d_in[3];
    const float* qm = (const float*)d_in[4];
    const float* Wq = (const float*)d_in[5];
    const float* Wk = (const float*)d_in[6];
    const float* Wv = (const float*)d_in[7];
    float* out = (float*)d_out;

    unsigned short* ws  = (unsigned short*)d_ws;
    unsigned short* Wtq = ws;                         // 3 x 1M bf16 (transposed weights)
    unsigned short* Wtk = Wtq + (1u << 20);
    unsigned short* Wtv = Wtk + (1u << 20);
    unsigned short* Qp  = Wtv + (1u << 20);           // 3 x 8M bf16 (projected Q, K, V^T)
    unsigned short* Kp  = Qp + (1u << 23);
    unsigned short* Vtp = Kp + (1u << 23);
    // d_out (32 MB) doubles as bf16 activation scratch (two 16 MB halves);
    // attn fully overwrites d_out afterwards
    unsigned short* Aq = (unsigned short*)d_out;
    unsigned short* Ak = Aq + (1u << 23);

    wt_kernel<<<dim3(32, 32, 3), dim3(32, 8), 0, stream>>>(Wq, Wk, Wv, Wtq, Wtk, Wtv);
    cvt2_kernel<<<dim3(4096, 2), 256, 0, stream>>>(q, k, Aq, Ak);
    proj_kernel<<<dim3(64, 8, 2), 256, 0, stream>>>(Aq, Ak, Wtq, Wtk, Qp, Kp, 0);
    cvt2_kernel<<<dim3(4096, 1), 256, 0, stream>>>(v, v, Aq, Aq);
    proj_kernel<<<dim3(64, 8, 1), 256, 0, stream>>>(Aq, Aq, Wtv, Wtv, Vtp, Vtp, 1);
    attn_kernel<<<dim3(64, 16), 256, 0, stream>>>(Qp, Kp, Vtp, vm, qm, out);
}

// Round 5
// 278.098 us; speedup vs baseline: 1.2991x; 1.2991x over previous
//
#include <hip/hip_runtime.h>
#include <hip/hip_bf16.h>

typedef __bf16 bf16x8 __attribute__((ext_vector_type(8)));
typedef float f32x4 __attribute__((ext_vector_type(4)));
typedef unsigned int u32;
typedef u32 u32x4 __attribute__((ext_vector_type(4)));

#define MFMA16(a, b, c) __builtin_amdgcn_mfma_f32_16x16x32_bf16(a, b, c, 0, 0, 0)

static __device__ __forceinline__ unsigned short f2b(float f) {
    __hip_bfloat16 b = __float2bfloat16(f);
    return __builtin_bit_cast(unsigned short, b);
}
static __device__ __forceinline__ float b2f(unsigned short u) {
    u32 v = ((u32)u) << 16;
    return __builtin_bit_cast(float, v);
}
static __device__ __forceinline__ u32 pk2(float lo, float hi) {  // 2x trunc-bf16 pack
    return (__builtin_bit_cast(u32, lo) >> 16) | (__builtin_bit_cast(u32, hi) & 0xFFFF0000u);
}
static __device__ __forceinline__ void glds16(const void* g, void* l) {
    __builtin_amdgcn_global_load_lds((const __attribute__((address_space(1))) u32*)g,
                                     (__attribute__((address_space(3))) u32*)l, 16, 0, 0);
}
// kv permutation within each 32-block of the V^T column axis (PV A/B k-order)
static __device__ __forceinline__ int vperm(int t) {  // t in [0,64)
    return (t & 32) | ((t & 12) << 1) | ((t & 16) >> 2) | (t & 3);
}

// ---------------- fp32 -> bf16 convert (activations), 8 elems/thread, y picks src ------
__global__ __launch_bounds__(256) void cvt2_kernel(const float* __restrict__ s0,
        const float* __restrict__ s1, unsigned short* __restrict__ d0,
        unsigned short* __restrict__ d1) {
    const float* src = blockIdx.y ? s1 : s0;
    unsigned short* dst = blockIdx.y ? d1 : d0;
    const size_t i = ((size_t)blockIdx.x * 256 + threadIdx.x) * 8;
    float4 a = *(const float4*)(src + i);
    float4 b = *(const float4*)(src + i + 4);
    ushort4 u0 = { f2b(a.x), f2b(a.y), f2b(a.z), f2b(a.w) };
    ushort4 u1 = { f2b(b.x), f2b(b.y), f2b(b.z), f2b(b.w) };
    *(ushort4*)(dst + i) = u0;
    *(ushort4*)(dst + i + 4) = u1;
}

// ---------------- weight transpose + bf16 cast: Wt[n][k] = bf16(W[k][n]) ----------------
__global__ void wt_kernel(const float* __restrict__ W0, const float* __restrict__ W1,
                          const float* __restrict__ W2, unsigned short* __restrict__ T0,
                          unsigned short* __restrict__ T1, unsigned short* __restrict__ T2) {
    const float* W = blockIdx.z == 0 ? W0 : (blockIdx.z == 1 ? W1 : W2);
    unsigned short* T = blockIdx.z == 0 ? T0 : (blockIdx.z == 1 ? T1 : T2);
    __shared__ float tile[32][33];
    const int n0 = blockIdx.x * 32, k0 = blockIdx.y * 32;
    const int tx = threadIdx.x, ty = threadIdx.y;  // block (32, 8)
#pragma unroll
    for (int i = 0; i < 4; i++)
        tile[ty + 8 * i][tx] = W[(size_t)(k0 + ty + 8 * i) * 1024 + n0 + tx];
    __syncthreads();
#pragma unroll
    for (int i = 0; i < 4; i++)
        T[(size_t)(n0 + ty + 8 * i) * 1024 + k0 + tx] = f2b(tile[tx][ty + 8 * i]);
}

// ---------------- projection GEMM, BK=64 (m97-style): dst = bf16(A @ Wt^T) -------------
// A: [8192][1024] bf16.  Wt: [1024 n][1024 k] bf16.  blockIdx.z picks A/Wt/dst pair.
// vmode 0: dst[(b*16+h)*2048 + s][64] (Q,K)
// vmode 1: dst[(b*16+h)*64 + d][2048] (V^T), kv axis vperm-permuted per 32-block
__global__ __launch_bounds__(256) void proj_kernel(
        const unsigned short* __restrict__ A0, const unsigned short* __restrict__ A1,
        const unsigned short* __restrict__ W0, const unsigned short* __restrict__ W1,
        unsigned short* __restrict__ D0, unsigned short* __restrict__ D1, const int vmode) {
    __shared__ unsigned short smem[17408];   // staging 32 KB (2x [2][128][32]) | Tw 34 KB
    unsigned short* As = smem;
    unsigned short* Bs = smem + 8192;
    const unsigned short* A  = blockIdx.z ? A1 : A0;
    const unsigned short* Wt = blockIdx.z ? W1 : W0;
    unsigned short* dst      = blockIdx.z ? D1 : D0;
    const int m0 = blockIdx.x * 128, n0 = blockIdx.y * 128;  // x=m (64): same-A -> same XCD
    const int tid = threadIdx.x;
    const int w = tid >> 6, lane = tid & 63, quad = lane >> 4, l16 = lane & 15;
    const int wr = (w >> 1) * 64, wc = (w & 1) * 64;
    // staging map: idx in [0,1024): panel=idx>>9 (k-half), row=(idx>>2)&127, c=idx&3
    const unsigned short* ap[4];
    const unsigned short* bp[4];
#pragma unroll
    for (int i = 0; i < 4; i++) {
        int idx = tid + i * 256;
        int row = (idx >> 2) & 127, ch = (idx >> 9) * 4 + (idx & 3);
        ap[i] = A + (size_t)(m0 + row) * 1024 + ch * 8;
        bp[i] = Wt + (size_t)(n0 + row) * 1024 + ch * 8;
    }
    f32x4 acc[4][4] = {};
    for (int kb = 0; kb < 16; kb++) {
        __syncthreads();
#pragma unroll
        for (int i = 0; i < 4; i++) {
            glds16(ap[i], &As[(tid + i * 256) * 8]);
            glds16(bp[i], &Bs[(tid + i * 256) * 8]);
            ap[i] += 64; bp[i] += 64;
        }
        __syncthreads();
#pragma unroll
        for (int kp = 0; kp < 2; kp++) {
            bf16x8 af[4], bf[4];
#pragma unroll
            for (int mt = 0; mt < 4; mt++)
                af[mt] = *(const bf16x8*)&As[kp * 4096 + (wr + mt * 16 + l16) * 32 + quad * 8];
#pragma unroll
            for (int nt = 0; nt < 4; nt++)
                bf[nt] = *(const bf16x8*)&Bs[kp * 4096 + (wc + nt * 16 + l16) * 32 + quad * 8];
#pragma unroll
            for (int mt = 0; mt < 4; mt++)
#pragma unroll
                for (int nt = 0; nt < 4; nt++)
                    acc[mt][nt] = MFMA16(af[mt], bf[nt], acc[mt][nt]);
        }
    }
    __syncthreads();                         // staging dead; reuse as transpose buffer
    unsigned short* Tw = smem + w * 4352;    // per-wave 64 x 68
    if (vmode == 0) {                        // rows = tokens, cols = channels
#pragma unroll
        for (int mt = 0; mt < 4; mt++)
#pragma unroll
            for (int nt = 0; nt < 4; nt++)
#pragma unroll
                for (int r = 0; r < 4; r++)
                    Tw[(mt * 16 + quad * 4 + r) * 68 + nt * 16 + l16] = f2b(acc[mt][nt][r]);
    } else {                                 // rows = d, cols = tokens (vperm order)
#pragma unroll
        for (int mt = 0; mt < 4; mt++)
#pragma unroll
            for (int nt = 0; nt < 4; nt++)
#pragma unroll
                for (int r = 0; r < 4; r++)
                    Tw[(nt * 16 + l16) * 68 + vperm(mt * 16 + quad * 4 + r)] = f2b(acc[mt][nt][r]);
    }
    const int gr0 = m0 + wr, gc0 = n0 + wc;  // wave-private buffer: in-wave order, no barrier
    const int b = gr0 >> 11, s0 = gr0 & 2047, h = gc0 >> 6;
    if (vmode == 0) {
        const size_t obase = (size_t)(b * 16 + h) * 2048;
#pragma unroll
        for (int j = 0; j < 16; j++) {
            int row = j * 4 + quad;          // token offset
            uint2 val = *(const uint2*)&Tw[row * 68 + l16 * 4];
            *(uint2*)(dst + (obase + s0 + row) * 64 + l16 * 4) = val;
        }
    } else {
        const size_t vbase = (size_t)(b * 16 + h) * 64 * 2048;
#pragma unroll
        for (int j = 0; j < 16; j++) {
            int row = j * 4 + quad;          // d
            uint2 val = *(const uint2*)&Tw[row * 68 + l16 * 4];
            *(uint2*)(dst + vbase + (size_t)row * 2048 + s0 + l16 * 4) = val;
        }
    }
}

// ---------------- fused masked-causal flash attention (BQ=128, S^T form) ----------------
// Qp,Kp: [bh][2048][64] bf16.  Vt: [bh][64][2048] bf16 (kv vperm'd).  out: fp32.
// S^T = K Q^T so P exits QK^T in A-operand lane distribution (col=lane&15=q);
// PV B-fragments are single b128 reads thanks to the global kv permutation.
// Fixed-max softmax e^(s-8): masked entries underflow to exact 0. Degenerate rows
// (all-prefix-masked, l==0) get the reference's uniform average via rare fix-up.
// Each wave owns 32 q rows (2 chunks); q-tile pairs {y, 15-y}: uniform 34 kv-iters.
__global__ __launch_bounds__(256) void attn_kernel(
        const unsigned short* __restrict__ Qp, const unsigned short* __restrict__ Kp,
        const unsigned short* __restrict__ Vt, const float* __restrict__ vmask,
        const float* __restrict__ qmask, float* __restrict__ out) {
    __shared__ unsigned short Ks[4096];      // [d-half][kv 64][32]
    __shared__ unsigned short Vts[4096];     // [kv-half][d 64][32] (vperm'd kv)
    __shared__ float Vmb[2048];              // key-mask bias (log2 domain), incl. -8
    const int bh = blockIdx.x, b = bh >> 4, h = bh & 15;
    const int tid = threadIdx.x;
    const int w = tid >> 6, lane = tid & 63, quad = lane >> 4, l16 = lane & 15;
    const size_t base = (size_t)bh * 2048 * 64;
    const float C1 = 0.18033688f;            // 0.125 * log2(e)
    const float C0 = -11.54156036f;          // -8 * log2(e)
    const float CM = -1.44269504e10f;        // -1e10 * log2(e)
    for (int i = tid; i < 2048; i += 256)
        Vmb[i] = (vmask[b * 2048 + i] != 0.f) ? C0 : (C0 + CM);

    // per-thread staging pointers (fixed row/chunk; tile offset added per kt)
    const int i0 = tid, i1 = tid + 256;      // panel=idx>>8, row=(idx>>2)&63, c=idx&3
    const unsigned short* kp0 = Kp + base + (size_t)((i0 >> 2) & 63) * 64 + (i0 >> 8) * 32 + (i0 & 3) * 8;
    const unsigned short* kp1 = Kp + base + (size_t)((i1 >> 2) & 63) * 64 + (i1 >> 8) * 32 + (i1 & 3) * 8;
    const unsigned short* vp0 = Vt + base + (size_t)((i0 >> 2) & 63) * 2048 + (i0 >> 8) * 32 + (i0 & 3) * 8;
    const unsigned short* vp1 = Vt + base + (size_t)((i1 >> 2) & 63) * 2048 + (i1 >> 8) * 32 + (i1 & 3) * 8;

    for (int pass = 0; pass < 2; pass++) {
        const int qt = pass ? 15 - blockIdx.y : blockIdx.y;
        const int q0 = qt * 128;
        bf16x8 qa[2][2];
#pragma unroll
        for (int qc = 0; qc < 2; qc++)
#pragma unroll
            for (int ks = 0; ks < 2; ks++)
                qa[qc][ks] = *(const bf16x8*)(Qp + base +
                    (size_t)(q0 + w * 32 + qc * 16 + l16) * 64 + ks * 32 + quad * 8);
        f32x4 o[2][4] = {};
        float lsum[2] = {0.f, 0.f};

        auto do_tile = [&](int kt, bool diag) __attribute__((always_inline)) {
            __syncthreads();                 // prev-iter/prev-pass LDS reads done
            glds16(kp0 + (size_t)kt * 4096, &Ks[i0 * 8]);
            glds16(kp1 + (size_t)kt * 4096, &Ks[i1 * 8]);
            glds16(vp0 + kt * 64, &Vts[i0 * 8]);
            glds16(vp1 + kt * 64, &Vts[i1 * 8]);
            __syncthreads();

            f32x4 st[2][4];                  // S^T = K Q^T: col=l16=q, row=quad*4+r=kv
#pragma unroll
            for (int nt = 0; nt < 4; nt++) {
                bf16x8 kf0 = *(const bf16x8*)&Ks[(nt * 16 + l16) * 32 + quad * 8];
                bf16x8 kf1 = *(const bf16x8*)&Ks[2048 + (nt * 16 + l16) * 32 + quad * 8];
#pragma unroll
                for (int qc = 0; qc < 2; qc++) {
                    f32x4 z = {};
                    z = MFMA16(kf0, qa[qc][0], z);
                    z = MFMA16(kf1, qa[qc][1], z);
                    st[qc][nt] = z;
                }
            }
            float p[2][4][4];
#pragma unroll
            for (int nt = 0; nt < 4; nt++) {
                f32x4 vb4 = *(const f32x4*)&Vmb[kt * 64 + nt * 16 + quad * 4];
#pragma unroll
                for (int qc = 0; qc < 2; qc++) {
                    const int thr = w * 32 + qc * 16 + l16 - (kt - 2 * qt) * 64;
#pragma unroll
                    for (int r = 0; r < 4; r++) {
                        float pv = __builtin_amdgcn_exp2f(st[qc][nt][r] * C1 + vb4[r]);
                        if (diag)            // causal mask (diagonal tiles only)
                            pv = (nt * 16 + quad * 4 + r > thr) ? 0.f : pv;
                        p[qc][nt][r] = pv;
                        lsum[qc] += pv;
                    }
                }
            }
            // O += P V; k-order = vperm (matches V's global permutation)
#pragma unroll
            for (int h2 = 0; h2 < 2; h2++) {
                bf16x8 pa[2];
#pragma unroll
                for (int qc = 0; qc < 2; qc++) {
                    u32x4 pw = { pk2(p[qc][2 * h2][0], p[qc][2 * h2][1]),
                                 pk2(p[qc][2 * h2][2], p[qc][2 * h2][3]),
                                 pk2(p[qc][2 * h2 + 1][0], p[qc][2 * h2 + 1][1]),
                                 pk2(p[qc][2 * h2 + 1][2], p[qc][2 * h2 + 1][3]) };
                    pa[qc] = __builtin_bit_cast(bf16x8, pw);
                }
#pragma unroll
                for (int dt = 0; dt < 4; dt++) {
                    bf16x8 vb = *(const bf16x8*)&Vts[h2 * 2048 + (dt * 16 + l16) * 32 + quad * 8];
#pragma unroll
                    for (int qc = 0; qc < 2; qc++)
                        o[qc][dt] = MFMA16(pa[qc], vb, o[qc][dt]);
                }
            }
        };
        for (int kt = 0; kt < 2 * qt; kt++) do_tile(kt, false);
        do_tile(2 * qt, true);
        do_tile(2 * qt + 1, true);

        float lr[2][4];                      // reduce l across quads: l[q]
#pragma unroll
        for (int qc = 0; qc < 2; qc++) {
            float lf = lsum[qc];
            lf += __shfl_xor(lf, 16);
            lf += __shfl_xor(lf, 32);
#pragma unroll
            for (int r = 0; r < 4; r++) lr[qc][r] = __shfl(lf, quad * 4 + r);
        }
        // degenerate rows (entire causal prefix v-masked): uniform average over
        // {kv <= q} u {kv > q : vmask==1}  (indexing V via vperm)
        bool deg = false;
#pragma unroll
        for (int qc = 0; qc < 2; qc++)
#pragma unroll
            for (int r = 0; r < 4; r++) deg |= (lr[qc][r] == 0.f);
        if (__any((int)deg)) {
#pragma unroll
            for (int qc = 0; qc < 2; qc++)
#pragma unroll
                for (int r = 0; r < 4; r++)
                    if (lr[qc][r] == 0.f) {
                        const int qr = q0 + w * 32 + qc * 16 + quad * 4 + r;
                        float cnt = 0.f;
                        float oacc[4] = {0.f, 0.f, 0.f, 0.f};
                        for (int kv = 0; kv < 2048; kv++) {
                            bool keep = (kv <= qr) || (vmask[b * 2048 + kv] != 0.f);
                            if (keep) {
                                int col = (kv & ~63) | vperm(kv & 63);
                                cnt += 1.f;
#pragma unroll
                                for (int dt = 0; dt < 4; dt++)
                                    oacc[dt] += b2f(Vt[base + (size_t)(dt * 16 + l16) * 2048 + col]);
                            }
                        }
                        lr[qc][r] = cnt;
#pragma unroll
                        for (int dt = 0; dt < 4; dt++) o[qc][dt][r] = oacc[dt];
                    }
        }
#pragma unroll
        for (int qc = 0; qc < 2; qc++)
#pragma unroll
            for (int r = 0; r < 4; r++) {
                int q = q0 + w * 32 + qc * 16 + quad * 4 + r;
                float sc = qmask[b * 2048 + q] / lr[qc][r];
#pragma unroll
                for (int dt = 0; dt < 4; dt++)
                    out[(size_t)(b * 2048 + q) * 1024 + h * 64 + dt * 16 + l16] = o[qc][dt][r] * sc;
            }
    }
}

extern "C" void kernel_launch(void* const* d_in, const int* in_sizes, int n_in,
                              void* d_out, int out_size, void* d_ws, size_t ws_size,
                              hipStream_t stream) {
    const float* q  = (const float*)d_in[0];
    const float* k  = (const float*)d_in[1];
    const float* v  = (const float*)d_in[2];
    const float* vm = (const float*)d_in[3];
    const float* qm = (const float*)d_in[4];
    const float* Wq = (const float*)d_in[5];
    const float* Wk = (const float*)d_in[6];
    const float* Wv = (const float*)d_in[7];
    float* out = (float*)d_out;

    unsigned short* ws  = (unsigned short*)d_ws;
    unsigned short* Wtq = ws;                         // 3 x 1M bf16 (transposed weights)
    unsigned short* Wtk = Wtq + (1u << 20);
    unsigned short* Wtv = Wtk + (1u << 20);
    unsigned short* Qp  = Wtv + (1u << 20);           // 3 x 8M bf16 (projected Q, K, V^T)
    unsigned short* Kp  = Qp + (1u << 23);
    unsigned short* Vtp = Kp + (1u << 23);
    // d_out (32 MB) doubles as bf16 activation scratch (two 16 MB halves);
    // attn fully overwrites d_out afterwards
    unsigned short* Aq = (unsigned short*)d_out;
    unsigned short* Ak = Aq + (1u << 23);

    wt_kernel<<<dim3(32, 32, 3), dim3(32, 8), 0, stream>>>(Wq, Wk, Wv, Wtq, Wtk, Wtv);
    cvt2_kernel<<<dim3(4096, 2), 256, 0, stream>>>(q, k, Aq, Ak);
    proj_kernel<<<dim3(64, 8, 2), 256, 0, stream>>>(Aq, Ak, Wtq, Wtk, Qp, Kp, 0);
    cvt2_kernel<<<dim3(4096, 1), 256, 0, stream>>>(v, v, Aq, Aq);
    proj_kernel<<<dim3(64, 8, 1), 256, 0, stream>>>(Aq, Aq, Wtv, Wtv, Vtp, Vtp, 1);
    attn_kernel<<<dim3(64, 8), 256, 0, stream>>>(Qp, Kp, Vtp, vm, qm, out);
}

// Round 6
// 273.958 us; speedup vs baseline: 1.3187x; 1.0151x over previous
//
#include <hip/hip_runtime.h>
#include <hip/hip_bf16.h>

typedef __bf16 bf16x8 __attribute__((ext_vector_type(8)));
typedef float f32x4 __attribute__((ext_vector_type(4)));
typedef unsigned int u32;
typedef u32 u32x4 __attribute__((ext_vector_type(4)));

#define MFMA16(a, b, c) __builtin_amdgcn_mfma_f32_16x16x32_bf16(a, b, c, 0, 0, 0)

static __device__ __forceinline__ unsigned short f2b(float f) {
    __hip_bfloat16 b = __float2bfloat16(f);
    return __builtin_bit_cast(unsigned short, b);
}
static __device__ __forceinline__ float b2f(unsigned short u) {
    u32 v = ((u32)u) << 16;
    return __builtin_bit_cast(float, v);
}
static __device__ __forceinline__ u32 pk2(float lo, float hi) {  // 2x trunc-bf16 pack
    return (__builtin_bit_cast(u32, lo) >> 16) | (__builtin_bit_cast(u32, hi) & 0xFFFF0000u);
}
static __device__ __forceinline__ void glds16(const void* g, void* l) {
    __builtin_amdgcn_global_load_lds((const __attribute__((address_space(1))) u32*)g,
                                     (__attribute__((address_space(3))) u32*)l, 16, 0, 0);
}
// kv permutation within each 32-block of the V^T column axis (PV A/B k-order)
static __device__ __forceinline__ int vperm(int t) {  // t in [0,64)
    return (t & 32) | ((t & 12) << 1) | ((t & 16) >> 2) | (t & 3);
}

// ---------------- fp32 -> bf16 convert (activations), 8 elems/thread, y picks src ------
__global__ __launch_bounds__(256) void cvt3_kernel(const float* __restrict__ s0,
        const float* __restrict__ s1, const float* __restrict__ s2,
        unsigned short* __restrict__ d0, unsigned short* __restrict__ d1,
        unsigned short* __restrict__ d2) {
    const int z = blockIdx.y;
    const float* src = z == 0 ? s0 : (z == 1 ? s1 : s2);
    unsigned short* dst = z == 0 ? d0 : (z == 1 ? d1 : d2);
    const size_t i = ((size_t)blockIdx.x * 256 + threadIdx.x) * 8;
    float4 a = *(const float4*)(src + i);
    float4 b = *(const float4*)(src + i + 4);
    ushort4 u0 = { f2b(a.x), f2b(a.y), f2b(a.z), f2b(a.w) };
    ushort4 u1 = { f2b(b.x), f2b(b.y), f2b(b.z), f2b(b.w) };
    *(ushort4*)(dst + i) = u0;
    *(ushort4*)(dst + i + 4) = u1;
}

// ---------------- weight transpose + bf16 cast: Wt[n][k] = bf16(W[k][n]) ----------------
__global__ void wt_kernel(const float* __restrict__ W0, const float* __restrict__ W1,
                          const float* __restrict__ W2, unsigned short* __restrict__ T0,
                          unsigned short* __restrict__ T1, unsigned short* __restrict__ T2) {
    const float* W = blockIdx.z == 0 ? W0 : (blockIdx.z == 1 ? W1 : W2);
    unsigned short* T = blockIdx.z == 0 ? T0 : (blockIdx.z == 1 ? T1 : T2);
    __shared__ float tile[32][33];
    const int n0 = blockIdx.x * 32, k0 = blockIdx.y * 32;
    const int tx = threadIdx.x, ty = threadIdx.y;  // block (32, 8)
#pragma unroll
    for (int i = 0; i < 4; i++)
        tile[ty + 8 * i][tx] = W[(size_t)(k0 + ty + 8 * i) * 1024 + n0 + tx];
    __syncthreads();
#pragma unroll
    for (int i = 0; i < 4; i++)
        T[(size_t)(n0 + ty + 8 * i) * 1024 + k0 + tx] = f2b(tile[tx][ty + 8 * i]);
}

// ---------------- projection GEMM, BK=64 (m97-style): dst = bf16(A @ Wt^T) -------------
// A: [8192][1024] bf16.  Wt: [1024 n][1024 k] bf16.  z (+zoff) picks the triple.
// z+zoff<2: dst[(b*16+h)*2048 + s][64] (Q,K)
// z+zoff==2: dst[(b*16+h)*64 + d][2048] (V^T), kv axis vperm-permuted per 32-block
__global__ __launch_bounds__(256) void proj_kernel(
        const unsigned short* __restrict__ A0, const unsigned short* __restrict__ A1,
        const unsigned short* __restrict__ A2,
        const unsigned short* __restrict__ W0, const unsigned short* __restrict__ W1,
        const unsigned short* __restrict__ W2,
        unsigned short* __restrict__ D0, unsigned short* __restrict__ D1,
        unsigned short* __restrict__ D2, const int zoff) {
    __shared__ unsigned short smem[17408];   // staging 32 KB (2x [2][128][32]) | Tw 34 KB
    unsigned short* As = smem;
    unsigned short* Bs = smem + 8192;
    const int z = blockIdx.z;
    const unsigned short* A  = z == 0 ? A0 : (z == 1 ? A1 : A2);
    const unsigned short* Wt = z == 0 ? W0 : (z == 1 ? W1 : W2);
    unsigned short* dst      = z == 0 ? D0 : (z == 1 ? D1 : D2);
    const int vmode = (z + zoff == 2);
    const int m0 = blockIdx.x * 128, n0 = blockIdx.y * 128;  // x=m (64): same-A -> same XCD
    const int tid = threadIdx.x;
    const int w = tid >> 6, lane = tid & 63, quad = lane >> 4, l16 = lane & 15;
    const int wr = (w >> 1) * 64, wc = (w & 1) * 64;
    // staging map: idx in [0,1024): panel=idx>>9 (k-half), row=(idx>>2)&127, c=idx&3
    const unsigned short* ap[4];
    const unsigned short* bp[4];
#pragma unroll
    for (int i = 0; i < 4; i++) {
        int idx = tid + i * 256;
        int row = (idx >> 2) & 127, ch = (idx >> 9) * 4 + (idx & 3);
        ap[i] = A + (size_t)(m0 + row) * 1024 + ch * 8;
        bp[i] = Wt + (size_t)(n0 + row) * 1024 + ch * 8;
    }
    f32x4 acc[4][4] = {};
    for (int kb = 0; kb < 16; kb++) {
        __syncthreads();
#pragma unroll
        for (int i = 0; i < 4; i++) {
            glds16(ap[i], &As[(tid + i * 256) * 8]);
            glds16(bp[i], &Bs[(tid + i * 256) * 8]);
            ap[i] += 64; bp[i] += 64;
        }
        __syncthreads();
#pragma unroll
        for (int kp = 0; kp < 2; kp++) {
            bf16x8 af[4], bf[4];
#pragma unroll
            for (int mt = 0; mt < 4; mt++)
                af[mt] = *(const bf16x8*)&As[kp * 4096 + (wr + mt * 16 + l16) * 32 + quad * 8];
#pragma unroll
            for (int nt = 0; nt < 4; nt++)
                bf[nt] = *(const bf16x8*)&Bs[kp * 4096 + (wc + nt * 16 + l16) * 32 + quad * 8];
#pragma unroll
            for (int mt = 0; mt < 4; mt++)
#pragma unroll
                for (int nt = 0; nt < 4; nt++)
                    acc[mt][nt] = MFMA16(af[mt], bf[nt], acc[mt][nt]);
        }
    }
    __syncthreads();                         // staging dead; reuse as transpose buffer
    unsigned short* Tw = smem + w * 4352;    // per-wave 64 x 68
    if (vmode == 0) {                        // rows = tokens, cols = channels
#pragma unroll
        for (int mt = 0; mt < 4; mt++)
#pragma unroll
            for (int nt = 0; nt < 4; nt++)
#pragma unroll
                for (int r = 0; r < 4; r++)
                    Tw[(mt * 16 + quad * 4 + r) * 68 + nt * 16 + l16] = f2b(acc[mt][nt][r]);
    } else {                                 // rows = d, cols = tokens (vperm order)
#pragma unroll
        for (int mt = 0; mt < 4; mt++)
#pragma unroll
            for (int nt = 0; nt < 4; nt++)
#pragma unroll
                for (int r = 0; r < 4; r++)
                    Tw[(nt * 16 + l16) * 68 + vperm(mt * 16 + quad * 4 + r)] = f2b(acc[mt][nt][r]);
    }
    const int gr0 = m0 + wr, gc0 = n0 + wc;  // wave-private buffer: in-wave order, no barrier
    const int b = gr0 >> 11, s0 = gr0 & 2047, h = gc0 >> 6;
    if (vmode == 0) {
        const size_t obase = (size_t)(b * 16 + h) * 2048;
#pragma unroll
        for (int j = 0; j < 16; j++) {
            int row = j * 4 + quad;          // token offset
            uint2 val = *(const uint2*)&Tw[row * 68 + l16 * 4];
            *(uint2*)(dst + (obase + s0 + row) * 64 + l16 * 4) = val;
        }
    } else {
        const size_t vbase = (size_t)(b * 16 + h) * 64 * 2048;
#pragma unroll
        for (int j = 0; j < 16; j++) {
            int row = j * 4 + quad;          // d
            uint2 val = *(const uint2*)&Tw[row * 68 + l16 * 4];
            *(uint2*)(dst + vbase + (size_t)row * 2048 + s0 + l16 * 4) = val;
        }
    }
}

// ---------------- fused masked-causal flash attention (BQ=128, S^T, dbuf pipeline) ------
// Qp,Kp: [bh][2048][64] bf16.  Vt: [bh][64][2048] bf16 (kv vperm'd).  out: fp32.
// S^T = K Q^T so P exits QK^T in A-operand lane distribution (col=lane&15=q);
// PV B-fragments are single b128 reads thanks to the global kv permutation.
// K/V staged via glds into double-buffered LDS with ONE barrier per tile: the
// barrier at loop top drains the prefetch issued a full compute-phase earlier.
// Fixed-max softmax e^(s-8): masked entries underflow to exact 0. Degenerate rows
// (all-prefix-masked, l==0) get the reference's uniform average via rare fix-up.
// Each wave owns 32 q rows (2 chunks); q-tile pairs {y, 15-y}: uniform 34 kv-iters.
__global__ __launch_bounds__(256) void attn_kernel(
        const unsigned short* __restrict__ Qp, const unsigned short* __restrict__ Kp,
        const unsigned short* __restrict__ Vt, const float* __restrict__ vmask,
        const float* __restrict__ qmask, float* __restrict__ out) {
    __shared__ unsigned short Ks[2][4096];   // [buf][d-half][kv 64][32]
    __shared__ unsigned short Vts[2][4096];  // [buf][kv-half][d 64][32] (vperm'd kv)
    __shared__ float Vmb[2048];              // key-mask bias (log2 domain), incl. -8
    const int bh = blockIdx.x, b = bh >> 4, h = bh & 15;
    const int tid = threadIdx.x;
    const int w = tid >> 6, lane = tid & 63, quad = lane >> 4, l16 = lane & 15;
    const size_t base = (size_t)bh * 2048 * 64;
    const float C1 = 0.18033688f;            // 0.125 * log2(e)
    const float C0 = -11.54156036f;          // -8 * log2(e)
    const float CM = -1.44269504e10f;        // -1e10 * log2(e)
    for (int i = tid; i < 2048; i += 256)
        Vmb[i] = (vmask[b * 2048 + i] != 0.f) ? C0 : (C0 + CM);

    // per-thread staging pointers (fixed row/chunk; tile offset added per kt)
    const int i0 = tid, i1 = tid + 256;      // panel=idx>>8, row=(idx>>2)&63, c=idx&3
    const unsigned short* kp0 = Kp + base + (size_t)((i0 >> 2) & 63) * 64 + (i0 >> 8) * 32 + (i0 & 3) * 8;
    const unsigned short* kp1 = Kp + base + (size_t)((i1 >> 2) & 63) * 64 + (i1 >> 8) * 32 + (i1 & 3) * 8;
    const unsigned short* vp0 = Vt + base + (size_t)((i0 >> 2) & 63) * 2048 + (i0 >> 8) * 32 + (i0 & 3) * 8;
    const unsigned short* vp1 = Vt + base + (size_t)((i1 >> 2) & 63) * 2048 + (i1 >> 8) * 32 + (i1 & 3) * 8;

    for (int pass = 0; pass < 2; pass++) {
        const int qt = pass ? 15 - blockIdx.y : blockIdx.y;
        const int q0 = qt * 128;
        bf16x8 qa[2][2];
#pragma unroll
        for (int qc = 0; qc < 2; qc++)
#pragma unroll
            for (int ks = 0; ks < 2; ks++)
                qa[qc][ks] = *(const bf16x8*)(Qp + base +
                    (size_t)(q0 + w * 32 + qc * 16 + l16) * 64 + ks * 32 + quad * 8);
        f32x4 o[2][4] = {};
        float lsum[2] = {0.f, 0.f};

        auto stage = [&](int kt, int sel) __attribute__((always_inline)) {
            glds16(kp0 + (size_t)kt * 4096, &Ks[sel][i0 * 8]);
            glds16(kp1 + (size_t)kt * 4096, &Ks[sel][i1 * 8]);
            glds16(vp0 + kt * 64, &Vts[sel][i0 * 8]);
            glds16(vp1 + kt * 64, &Vts[sel][i1 * 8]);
        };
        auto compute = [&](int kt, int sel, bool diag) __attribute__((always_inline)) {
            f32x4 st[2][4];                  // S^T = K Q^T: col=l16=q, row=quad*4+r=kv
#pragma unroll
            for (int nt = 0; nt < 4; nt++) {
                bf16x8 kf0 = *(const bf16x8*)&Ks[sel][(nt * 16 + l16) * 32 + quad * 8];
                bf16x8 kf1 = *(const bf16x8*)&Ks[sel][2048 + (nt * 16 + l16) * 32 + quad * 8];
#pragma unroll
                for (int qc = 0; qc < 2; qc++) {
                    f32x4 z = {};
                    z = MFMA16(kf0, qa[qc][0], z);
                    z = MFMA16(kf1, qa[qc][1], z);
                    st[qc][nt] = z;
                }
            }
            float p[2][4][4];
#pragma unroll
            for (int nt = 0; nt < 4; nt++) {
                f32x4 vb4 = *(const f32x4*)&Vmb[kt * 64 + nt * 16 + quad * 4];
#pragma unroll
                for (int qc = 0; qc < 2; qc++) {
                    const int thr = w * 32 + qc * 16 + l16 - (kt - 2 * qt) * 64;
#pragma unroll
                    for (int r = 0; r < 4; r++) {
                        float pv = __builtin_amdgcn_exp2f(st[qc][nt][r] * C1 + vb4[r]);
                        if (diag)            // causal mask (diagonal tiles only)
                            pv = (nt * 16 + quad * 4 + r > thr) ? 0.f : pv;
                        p[qc][nt][r] = pv;
                        lsum[qc] += pv;
                    }
                }
            }
            // O += P V; k-order = vperm (matches V's global permutation)
#pragma unroll
            for (int h2 = 0; h2 < 2; h2++) {
                bf16x8 pa[2];
#pragma unroll
                for (int qc = 0; qc < 2; qc++) {
                    u32x4 pw = { pk2(p[qc][2 * h2][0], p[qc][2 * h2][1]),
                                 pk2(p[qc][2 * h2][2], p[qc][2 * h2][3]),
                                 pk2(p[qc][2 * h2 + 1][0], p[qc][2 * h2 + 1][1]),
                                 pk2(p[qc][2 * h2 + 1][2], p[qc][2 * h2 + 1][3]) };
                    pa[qc] = __builtin_bit_cast(bf16x8, pw);
                }
#pragma unroll
                for (int dt = 0; dt < 4; dt++) {
                    bf16x8 vb = *(const bf16x8*)&Vts[sel][h2 * 2048 + (dt * 16 + l16) * 32 + quad * 8];
#pragma unroll
                    for (int qc = 0; qc < 2; qc++)
                        o[qc][dt] = MFMA16(pa[qc], vb, o[qc][dt]);
                }
            }
        };

        const int ntiles = 2 * qt + 2;
        __syncthreads();                     // prev-pass LDS reads done (also Vmb init)
        stage(0, 0);
        for (int kt = 0; kt < ntiles; kt++) {
            __syncthreads();                 // drains stage(kt); frees buf[(kt+1)&1]
            if (kt + 1 < ntiles) stage(kt + 1, (kt + 1) & 1);
            compute(kt, kt & 1, kt >= 2 * qt);
        }

        float lr[2][4];                      // reduce l across quads: l[q]
#pragma unroll
        for (int qc = 0; qc < 2; qc++) {
            float lf = lsum[qc];
            lf += __shfl_xor(lf, 16);
            lf += __shfl_xor(lf, 32);
#pragma unroll
            for (int r = 0; r < 4; r++) lr[qc][r] = __shfl(lf, quad * 4 + r);
        }
        // degenerate rows (entire causal prefix v-masked): uniform average over
        // {kv <= q} u {kv > q : vmask==1}  (indexing V via vperm)
        bool deg = false;
#pragma unroll
        for (int qc = 0; qc < 2; qc++)
#pragma unroll
            for (int r = 0; r < 4; r++) deg |= (lr[qc][r] == 0.f);
        if (__any((int)deg)) {
#pragma unroll
            for (int qc = 0; qc < 2; qc++)
#pragma unroll
                for (int r = 0; r < 4; r++)
                    if (lr[qc][r] == 0.f) {
                        const int qr = q0 + w * 32 + qc * 16 + quad * 4 + r;
                        float cnt = 0.f;
                        float oacc[4] = {0.f, 0.f, 0.f, 0.f};
                        for (int kv = 0; kv < 2048; kv++) {
                            bool keep = (kv <= qr) || (vmask[b * 2048 + kv] != 0.f);
                            if (keep) {
                                int col = (kv & ~63) | vperm(kv & 63);
                                cnt += 1.f;
#pragma unroll
                                for (int dt = 0; dt < 4; dt++)
                                    oacc[dt] += b2f(Vt[base + (size_t)(dt * 16 + l16) * 2048 + col]);
                            }
                        }
                        lr[qc][r] = cnt;
#pragma unroll
                        for (int dt = 0; dt < 4; dt++) o[qc][dt][r] = oacc[dt];
                    }
        }
#pragma unroll
        for (int qc = 0; qc < 2; qc++)
#pragma unroll
            for (int r = 0; r < 4; r++) {
                int q = q0 + w * 32 + qc * 16 + quad * 4 + r;
                float sc = qmask[b * 2048 + q] / lr[qc][r];
#pragma unroll
                for (int dt = 0; dt < 4; dt++)
                    out[(size_t)(b * 2048 + q) * 1024 + h * 64 + dt * 16 + l16] = o[qc][dt][r] * sc;
            }
    }
}

extern "C" void kernel_launch(void* const* d_in, const int* in_sizes, int n_in,
                              void* d_out, int out_size, void* d_ws, size_t ws_size,
                              hipStream_t stream) {
    const float* q  = (const float*)d_in[0];
    const float* k  = (const float*)d_in[1];
    const float* v  = (const float*)d_in[2];
    const float* vm = (const float*)d_in[3];
    const float* qm = (const float*)d_in[4];
    const float* Wq = (const float*)d_in[5];
    const float* Wk = (const float*)d_in[6];
    const float* Wv = (const float*)d_in[7];
    float* out = (float*)d_out;

    unsigned short* ws  = (unsigned short*)d_ws;
    unsigned short* Wtq = ws;                         // 3 x 1M bf16 (transposed weights)
    unsigned short* Wtk = Wtq + (1u << 20);
    unsigned short* Wtv = Wtk + (1u << 20);
    unsigned short* Qp  = Wtv + (1u << 20);           // 3 x 8M bf16 (projected Q, K, V^T)
    unsigned short* Kp  = Qp + (1u << 23);
    unsigned short* Vtp = Kp + (1u << 23);
    unsigned short* Av  = Vtp + (1u << 23);           // V activation scratch (ws tail)
    // d_out (32 MB) doubles as bf16 activation scratch (two 16 MB halves);
    // attn fully overwrites d_out afterwards
    unsigned short* Aq = (unsigned short*)d_out;
    unsigned short* Ak = Aq + (1u << 23);

    wt_kernel<<<dim3(32, 32, 3), dim3(32, 8), 0, stream>>>(Wq, Wk, Wv, Wtq, Wtk, Wtv);
    if (ws_size >= 73400320u) {              // Av fits in ws: single merged cvt + proj
        cvt3_kernel<<<dim3(4096, 3), 256, 0, stream>>>(q, k, v, Aq, Ak, Av);
        proj_kernel<<<dim3(64, 8, 3), 256, 0, stream>>>(Aq, Ak, Av, Wtq, Wtk, Wtv,
                                                        Qp, Kp, Vtp, 0);
    } else {                                 // fallback: two-stage (Av reuses d_out)
        cvt3_kernel<<<dim3(4096, 2), 256, 0, stream>>>(q, k, v, Aq, Ak, Ak);
        proj_kernel<<<dim3(64, 8, 2), 256, 0, stream>>>(Aq, Ak, Ak, Wtq, Wtk, Wtk,
                                                        Qp, Kp, Kp, 0);
        cvt3_kernel<<<dim3(4096, 1), 256, 0, stream>>>(v, v, v, Aq, Aq, Aq);
        proj_kernel<<<dim3(64, 8, 1), 256, 0, stream>>>(Aq, Aq, Aq, Wtv, Wtv, Wtv,
                                                        Vtp, Vtp, Vtp, 2);
    }
    attn_kernel<<<dim3(64, 8), 256, 0, stream>>>(Qp, Kp, Vtp, vm, qm, out);
}